// Round 1
// baseline (191.279 us; speedup 1.0000x reference)
//
#include <hip/hip_runtime.h>

// Problem constants (fixed by setup_inputs)
#define NNODES 27648
#define NEDGES 442368
#define FIN    256
#define HC     512
#define NH     4
#define CDIM   128
#define NAG    48
#define NGRP   12
#define N2     2304    // 48*48
#define NOUT   576     // 12*48
#define CAP    128     // max edges kept per output row (Poisson mean ~16)
#define EDIM   16

__device__ __forceinline__ float lrelu(float v, float s){ return v > 0.0f ? v : s * v; }

__device__ __forceinline__ float wsum(float v){
  #pragma unroll
  for (int off = 32; off; off >>= 1) v += __shfl_xor(v, off, 64);
  return v;
}
__device__ __forceinline__ float wmax(float v){
  #pragma unroll
  for (int off = 32; off; off >>= 1) v = fmaxf(v, __shfl_xor(v, off, 64));
  return v;
}

// K1: ws[f,h]=sum_c W[f,h,c]*att_src[h,c]; wd likewise; we[d,h]=sum_c W_edge[d,h,c]*att_edge[h,c];
//     zero easum + counts (ws is re-poisoned 0xAA before every launch).
__global__ __launch_bounds__(256) void k_init(
    const float* __restrict__ W, const float* __restrict__ att_src,
    const float* __restrict__ att_dst, const float* __restrict__ W_edge,
    const float* __restrict__ att_edge,
    float* __restrict__ ws_, float* __restrict__ wd_, float* __restrict__ we_,
    float* __restrict__ easum, int* __restrict__ counts){
  int g = blockIdx.x * 256 + threadIdx.x;
  if (g < 1024) {
    int f = g >> 2, h = g & 3;
    const float4* wp = (const float4*)(W + f*HC + h*CDIM);
    const float4* ap = (const float4*)(att_src + h*CDIM);
    float s = 0.f;
    #pragma unroll 8
    for (int c4 = 0; c4 < CDIM/4; c4++){
      float4 wv = wp[c4], av = ap[c4];
      s += wv.x*av.x + wv.y*av.y + wv.z*av.z + wv.w*av.w;
    }
    ws_[g] = s;
  } else if (g < 2048) {
    int gg = g - 1024; int f = gg >> 2, h = gg & 3;
    const float4* wp = (const float4*)(W + f*HC + h*CDIM);
    const float4* ap = (const float4*)(att_dst + h*CDIM);
    float s = 0.f;
    #pragma unroll 8
    for (int c4 = 0; c4 < CDIM/4; c4++){
      float4 wv = wp[c4], av = ap[c4];
      s += wv.x*av.x + wv.y*av.y + wv.z*av.z + wv.w*av.w;
    }
    wd_[gg] = s;
  } else if (g < 2112) {
    int gg = g - 2048; int d = gg >> 2, h = gg & 3;
    const float4* wp = (const float4*)(W_edge + d*HC + h*CDIM);
    const float4* ap = (const float4*)(att_edge + h*CDIM);
    float s = 0.f;
    #pragma unroll 8
    for (int c4 = 0; c4 < CDIM/4; c4++){
      float4 wv = wp[c4], av = ap[c4];
      s += wv.x*av.x + wv.y*av.y + wv.z*av.z + wv.w*av.w;
    }
    we_[gg] = s;
  } else if (g < 2128) {
    easum[g - 2112] = 0.f;
  } else if (g < 2128 + NOUT) {
    counts[g - 2128] = 0;
  }
}

// K2: column sums of edge_attr [E,16] -> easum (mean applied later via 1/E)
__global__ __launch_bounds__(256) void k_meansum(const float* __restrict__ ea,
                                                 float* __restrict__ easum){
  __shared__ float sd[256];
  int tid = threadIdx.x;
  int col = tid & 15, grp = tid >> 4;
  float acc = 0.f;
  for (int r = blockIdx.x*16 + grp; r < NEDGES; r += gridDim.x*16)
    acc += ea[(size_t)r*EDIM + col];
  sd[tid] = acc;
  __syncthreads();
  if (tid < 16) {
    float t = 0.f;
    #pragma unroll
    for (int i = 0; i < 16; i++) t += sd[i*16 + tid];
    atomicAdd(&easum[tid], t);
  }
}

// K3: bin edges whose dst is a diagonal node; precompute a_edge[4] per kept edge.
__global__ __launch_bounds__(256) void k_scan(const int* __restrict__ ei,
    const float* __restrict__ ea, const float* __restrict__ we_,
    int* __restrict__ counts, int* __restrict__ slist, float* __restrict__ aed){
  int e = blockIdx.x*256 + threadIdx.x;
  if (e >= NEDGES) return;
  int dst = ei[NEDGES + e];
  int r = dst % N2;
  if (r % 49) return;
  int row = (dst / N2) * NAG + r / 49;
  int pos = atomicAdd(&counts[row], 1);
  if (pos >= CAP) return;
  slist[row*CAP + pos] = ei[e];
  const float* eap = ea + (size_t)e*EDIM;
  float a0=0.f,a1=0.f,a2=0.f,a3=0.f;
  #pragma unroll
  for (int d = 0; d < EDIM; d++){
    float v = eap[d];
    a0 += v*we_[d*4+0]; a1 += v*we_[d*4+1]; a2 += v*we_[d*4+2]; a3 += v*we_[d*4+3];
  }
  float* ap = aed + (size_t)(row*CAP+pos)*4;
  ap[0]=a0; ap[1]=a1; ap[2]=a2; ap[3]=a3;
}

// K4: per output row: logits -> segment softmax -> z[row,h,:]=sum_e alpha*x[src]
__global__ __launch_bounds__(256) void k_attn(const float* __restrict__ x,
    const float* __restrict__ ws_, const float* __restrict__ wd_,
    const float* __restrict__ we_, const float* __restrict__ easum,
    const int* __restrict__ counts, const int* __restrict__ slist,
    const float* __restrict__ aed, float* __restrict__ z){
  __shared__ float lg[(CAP+1)*4];
  __shared__ int   srcs[CAP];
  __shared__ float adst_s[4];
  int row = blockIdx.x;
  int g = row / NAG, j = row - g*NAG;
  int dst = g*N2 + j*49;
  int tid = threadIdx.x;
  int lane = tid & 63, wave = tid >> 6;
  int k = counts[row]; if (k > CAP) k = CAP;

  // per-lane slice of ws (f = lane*4+q, all 4 heads)
  float wsr[4][4];
  #pragma unroll
  for (int q = 0; q < 4; q++){
    float4 t = *(const float4*)(ws_ + (lane*4+q)*4);
    wsr[q][0]=t.x; wsr[q][1]=t.y; wsr[q][2]=t.z; wsr[q][3]=t.w;
  }

  // edges round-robin over 4 waves
  for (int i = wave; i < k; i += 4){
    int src = slist[row*CAP + i];
    float4 aedv = *(const float4*)(aed + (size_t)(row*CAP+i)*4);
    float4 xv = *(const float4*)(x + (size_t)src*FIN + lane*4);
    float p0 = xv.x*wsr[0][0] + xv.y*wsr[1][0] + xv.z*wsr[2][0] + xv.w*wsr[3][0];
    float p1 = xv.x*wsr[0][1] + xv.y*wsr[1][1] + xv.z*wsr[2][1] + xv.w*wsr[3][1];
    float p2 = xv.x*wsr[0][2] + xv.y*wsr[1][2] + xv.z*wsr[2][2] + xv.w*wsr[3][2];
    float p3 = xv.x*wsr[0][3] + xv.y*wsr[1][3] + xv.z*wsr[2][3] + xv.w*wsr[3][3];
    p0 = wsum(p0); p1 = wsum(p1); p2 = wsum(p2); p3 = wsum(p3);
    if (lane == 0){
      srcs[i] = src;
      lg[i*4+0] = p0 + aedv.x; lg[i*4+1] = p1 + aedv.y;
      lg[i*4+2] = p2 + aedv.z; lg[i*4+3] = p3 + aedv.w;
    }
  }

  // wave 0: a_dst, self-loop logit (a_src(dst) + mean_ea@we)
  if (wave == 0){
    float wdr[4][4];
    #pragma unroll
    for (int q = 0; q < 4; q++){
      float4 t = *(const float4*)(wd_ + (lane*4+q)*4);
      wdr[q][0]=t.x; wdr[q][1]=t.y; wdr[q][2]=t.z; wdr[q][3]=t.w;
    }
    float4 xv = *(const float4*)(x + (size_t)dst*FIN + lane*4);
    float pd[4], ps[4];
    #pragma unroll
    for (int h = 0; h < 4; h++){
      pd[h] = xv.x*wdr[0][h] + xv.y*wdr[1][h] + xv.z*wdr[2][h] + xv.w*wdr[3][h];
      ps[h] = xv.x*wsr[0][h] + xv.y*wsr[1][h] + xv.z*wsr[2][h] + xv.w*wsr[3][h];
    }
    const float invE = 1.0f/(float)NEDGES;
    float md = (lane < 16) ? easum[lane]*invE : 0.f;
    float al[4];
    #pragma unroll
    for (int h = 0; h < 4; h++){
      float c = (lane < 16) ? md*we_[lane*4+h] : 0.f;
      al[h] = wsum(c);
      pd[h] = wsum(pd[h]);
      ps[h] = wsum(ps[h]);
    }
    if (lane == 0){
      #pragma unroll
      for (int h = 0; h < 4; h++){
        adst_s[h] = pd[h];
        lg[k*4+h] = ps[h] + al[h];
      }
    }
  }
  __syncthreads();

  // segment softmax: wave w handles head w over k+1 entries
  {
    int h = wave;
    float ad = adst_s[h];
    float m = -1e30f;
    for (int i = lane; i <= k; i += 64){
      float v = lrelu(lg[i*4+h] + ad, 0.2f);
      lg[i*4+h] = v;
      m = fmaxf(m, v);
    }
    m = wmax(m);
    float s = 0.f;
    for (int i = lane; i <= k; i += 64){
      float e = __expf(lg[i*4+h] - m);
      lg[i*4+h] = e;
      s += e;
    }
    s = wsum(s);
    float inv = 1.0f/(s + 1e-16f);
    for (int i = lane; i <= k; i += 64) lg[i*4+h] *= inv;
  }
  __syncthreads();

  // z accumulation: thread = feature f
  int f = tid;
  float a0=0.f,a1=0.f,a2=0.f,a3=0.f;
  for (int i = 0; i < k; i++){
    float xv = x[(size_t)srcs[i]*FIN + f];
    a0 += lg[i*4+0]*xv; a1 += lg[i*4+1]*xv; a2 += lg[i*4+2]*xv; a3 += lg[i*4+3]*xv;
  }
  {
    float xv = x[(size_t)dst*FIN + f];
    a0 += lg[k*4+0]*xv; a1 += lg[k*4+1]*xv; a2 += lg[k*4+2]*xv; a3 += lg[k*4+3]*xv;
  }
  float* zp = z + (size_t)row*1024;
  zp[0*256+f]=a0; zp[1*256+f]=a1; zp[2*256+f]=a2; zp[3*256+f]=a3;
}

// K5: h2[row, h*128+c] = lrelu( z[row,h,:] @ W[:, h*128+c] + bias, 0.01 )
__global__ __launch_bounds__(256) void k_gemm1(const float* __restrict__ z,
    const float* __restrict__ W, const float* __restrict__ bias,
    float* __restrict__ h2){
  __shared__ float zs[8*256];
  int base = blockIdx.x * 8;     // 72 row-blocks
  int h = blockIdx.y;            // head
  int tid = threadIdx.x;
  for (int idx = tid; idx < 2048; idx += 256){
    int r = idx >> 8, f = idx & 255;
    zs[idx] = z[(size_t)(base+r)*1024 + h*256 + f];
  }
  __syncthreads();
  int c = tid & 127, rq = tid >> 7;   // rq uniform per wave -> LDS broadcast
  float acc0=0.f, acc1=0.f, acc2=0.f, acc3=0.f;
  const float* Wp = W + h*CDIM + c;
  for (int f0 = 0; f0 < 256; f0 += 4){
    float w0 = Wp[(size_t)(f0+0)*HC];
    float w1 = Wp[(size_t)(f0+1)*HC];
    float w2 = Wp[(size_t)(f0+2)*HC];
    float w3 = Wp[(size_t)(f0+3)*HC];
    float4 z0 = *(const float4*)&zs[(rq*4+0)*256 + f0];
    float4 z1 = *(const float4*)&zs[(rq*4+1)*256 + f0];
    float4 z2 = *(const float4*)&zs[(rq*4+2)*256 + f0];
    float4 z3 = *(const float4*)&zs[(rq*4+3)*256 + f0];
    acc0 += z0.x*w0 + z0.y*w1 + z0.z*w2 + z0.w*w3;
    acc1 += z1.x*w0 + z1.y*w1 + z1.z*w2 + z1.w*w3;
    acc2 += z2.x*w0 + z2.y*w1 + z2.z*w2 + z2.w*w3;
    acc3 += z3.x*w0 + z3.y*w1 + z3.z*w2 + z3.w*w3;
  }
  int o = h*CDIM + c;
  float b = bias[o];
  h2[(size_t)(base + rq*4 + 0)*HC + o] = lrelu(acc0 + b, 0.01f);
  h2[(size_t)(base + rq*4 + 1)*HC + o] = lrelu(acc1 + b, 0.01f);
  h2[(size_t)(base + rq*4 + 2)*HC + o] = lrelu(acc2 + b, 0.01f);
  h2[(size_t)(base + rq*4 + 3)*HC + o] = lrelu(acc3 + b, 0.01f);
}

// K6: out[row, j] = lrelu( h2[row,:] @ fc_W[:,j] + fc_b[j], 0.01 )
__global__ __launch_bounds__(256) void k_gemm2(const float* __restrict__ h2,
    const float* __restrict__ fcW, const float* __restrict__ fcb,
    float* __restrict__ out){
  __shared__ float hs[4*512];
  int base = blockIdx.x * 4;     // 144 row-blocks
  int tid = threadIdx.x;
  for (int idx = tid; idx < 2048; idx += 256){
    hs[idx] = h2[(size_t)base*HC + idx];
  }
  __syncthreads();
  int j = tid;
  float acc0=0.f, acc1=0.f, acc2=0.f, acc3=0.f;
  for (int k0 = 0; k0 < 512; k0 += 4){
    float w0 = fcW[(size_t)(k0+0)*256 + j];
    float w1 = fcW[(size_t)(k0+1)*256 + j];
    float w2 = fcW[(size_t)(k0+2)*256 + j];
    float w3 = fcW[(size_t)(k0+3)*256 + j];
    float4 h0 = *(const float4*)&hs[0*512 + k0];
    float4 h1 = *(const float4*)&hs[1*512 + k0];
    float4 h2v = *(const float4*)&hs[2*512 + k0];
    float4 h3 = *(const float4*)&hs[3*512 + k0];
    acc0 += h0.x*w0 + h0.y*w1 + h0.z*w2 + h0.w*w3;
    acc1 += h1.x*w0 + h1.y*w1 + h1.z*w2 + h1.w*w3;
    acc2 += h2v.x*w0 + h2v.y*w1 + h2v.z*w2 + h2v.w*w3;
    acc3 += h3.x*w0 + h3.y*w1 + h3.z*w2 + h3.w*w3;
  }
  float b = fcb[j];
  out[(size_t)(base+0)*256 + j] = lrelu(acc0 + b, 0.01f);
  out[(size_t)(base+1)*256 + j] = lrelu(acc1 + b, 0.01f);
  out[(size_t)(base+2)*256 + j] = lrelu(acc2 + b, 0.01f);
  out[(size_t)(base+3)*256 + j] = lrelu(acc3 + b, 0.01f);
}

extern "C" void kernel_launch(void* const* d_in, const int* in_sizes, int n_in,
                              void* d_out, int out_size, void* d_ws, size_t ws_size,
                              hipStream_t stream) {
  const float* x        = (const float*)d_in[0];
  const int*   ei       = (const int*)  d_in[1];
  const float* ea       = (const float*)d_in[2];
  // d_in[3]=num_groups, d_in[4]=agents_per_group (fixed: 12, 48)
  const float* W        = (const float*)d_in[5];
  const float* att_src  = (const float*)d_in[6];
  const float* att_dst  = (const float*)d_in[7];
  const float* W_edge   = (const float*)d_in[8];
  const float* att_edge = (const float*)d_in[9];
  const float* bias     = (const float*)d_in[10];
  const float* fcW      = (const float*)d_in[11];
  const float* fcb      = (const float*)d_in[12];
  float* out = (float*)d_out;

  float* w = (float*)d_ws;
  float* ws_   = w;                 // 1024
  float* wd_   = w + 1024;          // 1024
  float* we_   = w + 2048;          // 64
  float* easum = w + 2112;          // 16
  int*   counts= (int*)(w + 2128);  // 576
  int*   slist = (int*)(w + 2704);  // 576*128 = 73728
  float* aed   = w + 76432;         // 576*128*4 = 294912
  float* z     = w + 371344;        // 576*1024 = 589824
  float* h2    = w + 961168;        // 576*512 = 294912  (total ~4.8 MB)

  k_init<<<11, 256, 0, stream>>>(W, att_src, att_dst, W_edge, att_edge,
                                 ws_, wd_, we_, easum, counts);
  k_meansum<<<256, 256, 0, stream>>>(ea, easum);
  k_scan<<<(NEDGES+255)/256, 256, 0, stream>>>(ei, ea, we_, counts, slist, aed);
  k_attn<<<NOUT, 256, 0, stream>>>(x, ws_, wd_, we_, easum, counts, slist, aed, z);
  k_gemm1<<<dim3(72,4), 256, 0, stream>>>(z, W, bias, h2);
  k_gemm2<<<144, 256, 0, stream>>>(h2, fcW, fcb, out);
}

// Round 2
// 163.499 us; speedup vs baseline: 1.1699x; 1.1699x over previous
//
#include <hip/hip_runtime.h>

// Problem constants (fixed by setup_inputs)
#define NNODES 27648
#define NEDGES 442368
#define FIN    256
#define HC     512
#define NH     4
#define CDIM   128
#define NAG    48
#define NGRP   12
#define N2     2304    // 48*48
#define NOUT   576     // 12*48
#define CAP    128     // max edges kept per output row (Poisson mean ~16)
#define EDIM   16
#define MPART  512     // meansum partial blocks

__device__ __forceinline__ float lrelu(float v, float s){ return v > 0.0f ? v : s * v; }

__device__ __forceinline__ float wsum(float v){
  #pragma unroll
  for (int off = 32; off; off >>= 1) v += __shfl_xor(v, off, 64);
  return v;
}
__device__ __forceinline__ float wmax(float v){
  #pragma unroll
  for (int off = 32; off; off >>= 1) v = fmaxf(v, __shfl_xor(v, off, 64));
  return v;
}

// K_A (fused): blocks 0..10  -> ws/wd/we precompute + zero counts
//              blocks 11..   -> edge_attr column partial sums (float4, grid-stride)
__global__ __launch_bounds__(256) void k_pre(
    const float* __restrict__ W, const float* __restrict__ att_src,
    const float* __restrict__ att_dst, const float* __restrict__ W_edge,
    const float* __restrict__ att_edge, const float* __restrict__ ea,
    float* __restrict__ ws_, float* __restrict__ wd_, float* __restrict__ we_,
    int* __restrict__ counts, float4* __restrict__ easum_part){
  int b = blockIdx.x;
  int tid = threadIdx.x;
  if (b < 11) {
    int g = b * 256 + tid;
    if (g < 1024) {
      int f = g >> 2, h = g & 3;
      const float4* wp = (const float4*)(W + f*HC + h*CDIM);
      const float4* ap = (const float4*)(att_src + h*CDIM);
      float s = 0.f;
      #pragma unroll 8
      for (int c4 = 0; c4 < CDIM/4; c4++){
        float4 wv = wp[c4], av = ap[c4];
        s += wv.x*av.x + wv.y*av.y + wv.z*av.z + wv.w*av.w;
      }
      ws_[g] = s;
    } else if (g < 2048) {
      int gg = g - 1024; int f = gg >> 2, h = gg & 3;
      const float4* wp = (const float4*)(W + f*HC + h*CDIM);
      const float4* ap = (const float4*)(att_dst + h*CDIM);
      float s = 0.f;
      #pragma unroll 8
      for (int c4 = 0; c4 < CDIM/4; c4++){
        float4 wv = wp[c4], av = ap[c4];
        s += wv.x*av.x + wv.y*av.y + wv.z*av.z + wv.w*av.w;
      }
      wd_[gg] = s;
    } else if (g < 2112) {
      int gg = g - 2048; int d = gg >> 2, h = gg & 3;
      const float4* wp = (const float4*)(W_edge + d*HC + h*CDIM);
      const float4* ap = (const float4*)(att_edge + h*CDIM);
      float s = 0.f;
      #pragma unroll 8
      for (int c4 = 0; c4 < CDIM/4; c4++){
        float4 wv = wp[c4], av = ap[c4];
        s += wv.x*av.x + wv.y*av.y + wv.z*av.z + wv.w*av.w;
      }
      we_[gg] = s;
    } else if (g < 2112 + NOUT) {
      counts[g - 2112] = 0;
    }
  } else {
    // edge_attr partial column sums; col-group = idx & 3 (invariant under stride)
    int pb = b - 11;
    const float4* p = (const float4*)ea;
    const int total = NEDGES * 4;           // float4 count
    float4 acc = make_float4(0.f, 0.f, 0.f, 0.f);
    for (int i = pb*256 + tid; i < total; i += MPART*256){
      float4 v = p[i];
      acc.x += v.x; acc.y += v.y; acc.z += v.z; acc.w += v.w;
    }
    // reduce across the 16 lanes sharing lane&3
    #pragma unroll
    for (int off = 4; off <= 32; off <<= 1){
      acc.x += __shfl_xor(acc.x, off, 64);
      acc.y += __shfl_xor(acc.y, off, 64);
      acc.z += __shfl_xor(acc.z, off, 64);
      acc.w += __shfl_xor(acc.w, off, 64);
    }
    __shared__ float4 sd4[16];
    int lane = tid & 63, wave = tid >> 6;
    if (lane < 4) sd4[wave*4 + lane] = acc;
    __syncthreads();
    if (tid < 4){
      float4 t = sd4[tid];
      float4 a = sd4[4+tid], c = sd4[8+tid], d = sd4[12+tid];
      t.x += a.x + c.x + d.x; t.y += a.y + c.y + d.y;
      t.z += a.z + c.z + d.z; t.w += a.w + c.w + d.w;
      easum_part[pb*4 + tid] = t;
    }
  }
}

// K_B: blocks 0..1727 bin edges whose dst is diagonal; block 1728 reduces easum.
__global__ __launch_bounds__(256) void k_scan(const int* __restrict__ ei,
    const float* __restrict__ ea, const float* __restrict__ we_,
    int* __restrict__ counts, int* __restrict__ slist, float* __restrict__ aed,
    const float* __restrict__ easum_part, float* __restrict__ easum){
  int tid = threadIdx.x;
  if (blockIdx.x == NEDGES/256){
    // reduce 512 partial blocks x 16 cols -> easum[16]
    int col = tid & 15, part = tid >> 4;          // 16 parts x 32 pblocks
    float s = 0.f;
    for (int pb = 0; pb < MPART/16; pb++)
      s += easum_part[(part*(MPART/16) + pb)*16 + col];
    __shared__ float sd[256];
    sd[tid] = s;
    __syncthreads();
    if (tid < 16){
      float t = 0.f;
      #pragma unroll
      for (int i = 0; i < 16; i++) t += sd[i*16 + tid];
      easum[tid] = t;
    }
    return;
  }
  int e = blockIdx.x*256 + tid;
  int dst = ei[NEDGES + e];
  int r = dst % N2;
  if (r % 49) return;
  int row = (dst / N2) * NAG + r / 49;
  int pos = atomicAdd(&counts[row], 1);
  if (pos >= CAP) return;
  slist[row*CAP + pos] = ei[e];
  const float* eap = ea + (size_t)e*EDIM;
  float a0=0.f,a1=0.f,a2=0.f,a3=0.f;
  #pragma unroll
  for (int d = 0; d < EDIM; d++){
    float v = eap[d];
    a0 += v*we_[d*4+0]; a1 += v*we_[d*4+1]; a2 += v*we_[d*4+2]; a3 += v*we_[d*4+3];
  }
  float* ap = aed + (size_t)(row*CAP+pos)*4;
  ap[0]=a0; ap[1]=a1; ap[2]=a2; ap[3]=a3;
}

// K_C: per output row: logits -> segment softmax -> z[row,h,:]=sum_e alpha*x[src]
__global__ __launch_bounds__(256) void k_attn(const float* __restrict__ x,
    const float* __restrict__ ws_, const float* __restrict__ wd_,
    const float* __restrict__ we_, const float* __restrict__ easum,
    const int* __restrict__ counts, const int* __restrict__ slist,
    const float* __restrict__ aed, float* __restrict__ z){
  __shared__ float lg[(CAP+1)*4];
  __shared__ int   srcs[CAP];
  __shared__ float adst_s[4];
  int row = blockIdx.x;
  int g = row / NAG, j = row - g*NAG;
  int dst = g*N2 + j*49;
  int tid = threadIdx.x;
  int lane = tid & 63, wave = tid >> 6;
  int k = counts[row]; if (k > CAP) k = CAP;

  // per-lane slice of ws (f = lane*4+q, all 4 heads)
  float wsr[4][4];
  #pragma unroll
  for (int q = 0; q < 4; q++){
    float4 t = *(const float4*)(ws_ + (lane*4+q)*4);
    wsr[q][0]=t.x; wsr[q][1]=t.y; wsr[q][2]=t.z; wsr[q][3]=t.w;
  }

  // edges round-robin over 4 waves
  for (int i = wave; i < k; i += 4){
    int src = slist[row*CAP + i];
    float4 aedv = *(const float4*)(aed + (size_t)(row*CAP+i)*4);
    float4 xv = *(const float4*)(x + (size_t)src*FIN + lane*4);
    float p0 = xv.x*wsr[0][0] + xv.y*wsr[1][0] + xv.z*wsr[2][0] + xv.w*wsr[3][0];
    float p1 = xv.x*wsr[0][1] + xv.y*wsr[1][1] + xv.z*wsr[2][1] + xv.w*wsr[3][1];
    float p2 = xv.x*wsr[0][2] + xv.y*wsr[1][2] + xv.z*wsr[2][2] + xv.w*wsr[3][2];
    float p3 = xv.x*wsr[0][3] + xv.y*wsr[1][3] + xv.z*wsr[2][3] + xv.w*wsr[3][3];
    p0 = wsum(p0); p1 = wsum(p1); p2 = wsum(p2); p3 = wsum(p3);
    if (lane == 0){
      srcs[i] = src;
      lg[i*4+0] = p0 + aedv.x; lg[i*4+1] = p1 + aedv.y;
      lg[i*4+2] = p2 + aedv.z; lg[i*4+3] = p3 + aedv.w;
    }
  }

  // wave 0: a_dst, self-loop logit (a_src(dst) + mean_ea@we)
  if (wave == 0){
    float wdr[4][4];
    #pragma unroll
    for (int q = 0; q < 4; q++){
      float4 t = *(const float4*)(wd_ + (lane*4+q)*4);
      wdr[q][0]=t.x; wdr[q][1]=t.y; wdr[q][2]=t.z; wdr[q][3]=t.w;
    }
    float4 xv = *(const float4*)(x + (size_t)dst*FIN + lane*4);
    float pd[4], ps[4];
    #pragma unroll
    for (int h = 0; h < 4; h++){
      pd[h] = xv.x*wdr[0][h] + xv.y*wdr[1][h] + xv.z*wdr[2][h] + xv.w*wdr[3][h];
      ps[h] = xv.x*wsr[0][h] + xv.y*wsr[1][h] + xv.z*wsr[2][h] + xv.w*wsr[3][h];
    }
    const float invE = 1.0f/(float)NEDGES;
    float md = (lane < 16) ? easum[lane]*invE : 0.f;
    float al[4];
    #pragma unroll
    for (int h = 0; h < 4; h++){
      float c = (lane < 16) ? md*we_[lane*4+h] : 0.f;
      al[h] = wsum(c);
      pd[h] = wsum(pd[h]);
      ps[h] = wsum(ps[h]);
    }
    if (lane == 0){
      #pragma unroll
      for (int h = 0; h < 4; h++){
        adst_s[h] = pd[h];
        lg[k*4+h] = ps[h] + al[h];
      }
    }
  }
  __syncthreads();

  // segment softmax: wave w handles head w over k+1 entries
  {
    int h = wave;
    float ad = adst_s[h];
    float m = -1e30f;
    for (int i = lane; i <= k; i += 64){
      float v = lrelu(lg[i*4+h] + ad, 0.2f);
      lg[i*4+h] = v;
      m = fmaxf(m, v);
    }
    m = wmax(m);
    float s = 0.f;
    for (int i = lane; i <= k; i += 64){
      float e = __expf(lg[i*4+h] - m);
      lg[i*4+h] = e;
      s += e;
    }
    s = wsum(s);
    float inv = 1.0f/(s + 1e-16f);
    for (int i = lane; i <= k; i += 64) lg[i*4+h] *= inv;
  }
  __syncthreads();

  // z accumulation: thread = feature f
  int f = tid;
  float a0=0.f,a1=0.f,a2=0.f,a3=0.f;
  for (int i = 0; i < k; i++){
    float xv = x[(size_t)srcs[i]*FIN + f];
    a0 += lg[i*4+0]*xv; a1 += lg[i*4+1]*xv; a2 += lg[i*4+2]*xv; a3 += lg[i*4+3]*xv;
  }
  {
    float xv = x[(size_t)dst*FIN + f];
    a0 += lg[k*4+0]*xv; a1 += lg[k*4+1]*xv; a2 += lg[k*4+2]*xv; a3 += lg[k*4+3]*xv;
  }
  float* zp = z + (size_t)row*1024;
  zp[0*256+f]=a0; zp[1*256+f]=a1; zp[2*256+f]=a2; zp[3*256+f]=a3;
}

// K_D: h2[row, h*128+c] = lrelu( z[row,h,:] @ W[:, h*128+c] + bias, 0.01 )
__global__ __launch_bounds__(256) void k_gemm1(const float* __restrict__ z,
    const float* __restrict__ W, const float* __restrict__ bias,
    float* __restrict__ h2){
  __shared__ float zs[8*256];
  int base = blockIdx.x * 8;     // 72 row-blocks
  int h = blockIdx.y;            // head
  int tid = threadIdx.x;
  for (int idx = tid; idx < 2048; idx += 256){
    int r = idx >> 8, f = idx & 255;
    zs[idx] = z[(size_t)(base+r)*1024 + h*256 + f];
  }
  __syncthreads();
  int c = tid & 127, rq = tid >> 7;   // rq uniform per wave -> LDS broadcast
  float acc0=0.f, acc1=0.f, acc2=0.f, acc3=0.f;
  const float* Wp = W + h*CDIM + c;
  for (int f0 = 0; f0 < 256; f0 += 4){
    float w0 = Wp[(size_t)(f0+0)*HC];
    float w1 = Wp[(size_t)(f0+1)*HC];
    float w2 = Wp[(size_t)(f0+2)*HC];
    float w3 = Wp[(size_t)(f0+3)*HC];
    float4 z0 = *(const float4*)&zs[(rq*4+0)*256 + f0];
    float4 z1 = *(const float4*)&zs[(rq*4+1)*256 + f0];
    float4 z2 = *(const float4*)&zs[(rq*4+2)*256 + f0];
    float4 z3 = *(const float4*)&zs[(rq*4+3)*256 + f0];
    acc0 += z0.x*w0 + z0.y*w1 + z0.z*w2 + z0.w*w3;
    acc1 += z1.x*w0 + z1.y*w1 + z1.z*w2 + z1.w*w3;
    acc2 += z2.x*w0 + z2.y*w1 + z2.z*w2 + z2.w*w3;
    acc3 += z3.x*w0 + z3.y*w1 + z3.z*w2 + z3.w*w3;
  }
  int o = h*CDIM + c;
  float b = bias[o];
  h2[(size_t)(base + rq*4 + 0)*HC + o] = lrelu(acc0 + b, 0.01f);
  h2[(size_t)(base + rq*4 + 1)*HC + o] = lrelu(acc1 + b, 0.01f);
  h2[(size_t)(base + rq*4 + 2)*HC + o] = lrelu(acc2 + b, 0.01f);
  h2[(size_t)(base + rq*4 + 3)*HC + o] = lrelu(acc3 + b, 0.01f);
}

// K_E: out[row, j] = lrelu( h2[row,:] @ fc_W[:,j] + fc_b[j], 0.01 )
__global__ __launch_bounds__(256) void k_gemm2(const float* __restrict__ h2,
    const float* __restrict__ fcW, const float* __restrict__ fcb,
    float* __restrict__ out){
  __shared__ float hs[4*512];
  int base = blockIdx.x * 4;     // 144 row-blocks
  int tid = threadIdx.x;
  for (int idx = tid; idx < 2048; idx += 256){
    hs[idx] = h2[(size_t)base*HC + idx];
  }
  __syncthreads();
  int j = tid;
  float acc0=0.f, acc1=0.f, acc2=0.f, acc3=0.f;
  for (int k0 = 0; k0 < 512; k0 += 4){
    float w0 = fcW[(size_t)(k0+0)*256 + j];
    float w1 = fcW[(size_t)(k0+1)*256 + j];
    float w2 = fcW[(size_t)(k0+2)*256 + j];
    float w3 = fcW[(size_t)(k0+3)*256 + j];
    float4 h0 = *(const float4*)&hs[0*512 + k0];
    float4 h1 = *(const float4*)&hs[1*512 + k0];
    float4 h2v = *(const float4*)&hs[2*512 + k0];
    float4 h3 = *(const float4*)&hs[3*512 + k0];
    acc0 += h0.x*w0 + h0.y*w1 + h0.z*w2 + h0.w*w3;
    acc1 += h1.x*w0 + h1.y*w1 + h1.z*w2 + h1.w*w3;
    acc2 += h2v.x*w0 + h2v.y*w1 + h2v.z*w2 + h2v.w*w3;
    acc3 += h3.x*w0 + h3.y*w1 + h3.z*w2 + h3.w*w3;
  }
  float b = fcb[j];
  out[(size_t)(base+0)*256 + j] = lrelu(acc0 + b, 0.01f);
  out[(size_t)(base+1)*256 + j] = lrelu(acc1 + b, 0.01f);
  out[(size_t)(base+2)*256 + j] = lrelu(acc2 + b, 0.01f);
  out[(size_t)(base+3)*256 + j] = lrelu(acc3 + b, 0.01f);
}

extern "C" void kernel_launch(void* const* d_in, const int* in_sizes, int n_in,
                              void* d_out, int out_size, void* d_ws, size_t ws_size,
                              hipStream_t stream) {
  const float* x        = (const float*)d_in[0];
  const int*   ei       = (const int*)  d_in[1];
  const float* ea       = (const float*)d_in[2];
  // d_in[3]=num_groups, d_in[4]=agents_per_group (fixed: 12, 48)
  const float* W        = (const float*)d_in[5];
  const float* att_src  = (const float*)d_in[6];
  const float* att_dst  = (const float*)d_in[7];
  const float* W_edge   = (const float*)d_in[8];
  const float* att_edge = (const float*)d_in[9];
  const float* bias     = (const float*)d_in[10];
  const float* fcW      = (const float*)d_in[11];
  const float* fcb      = (const float*)d_in[12];
  float* out = (float*)d_out;

  float* w = (float*)d_ws;
  float*  ws_       = w;                    // 1024
  float*  wd_       = w + 1024;             // 1024
  float*  we_       = w + 2048;             // 64
  float*  easum     = w + 2112;             // 16
  int*    counts    = (int*)(w + 2128);     // 576
  float*  easum_p   = w + 2704;             // 512*16 = 8192 (16B-aligned: 2704*4%16==0)
  int*    slist     = (int*)(w + 10896);    // 576*128 = 73728
  float*  aed       = w + 84624;            // 576*128*4 = 294912 (16B-aligned)
  float*  z         = w + 379536;           // 576*1024 = 589824
  float*  h2        = w + 969360;           // 576*512 = 294912   (total ~5.1 MB)

  k_pre<<<11 + MPART, 256, 0, stream>>>(W, att_src, att_dst, W_edge, att_edge, ea,
                                        ws_, wd_, we_, counts, (float4*)easum_p);
  k_scan<<<NEDGES/256 + 1, 256, 0, stream>>>(ei, ea, we_, counts, slist, aed,
                                             easum_p, easum);
  k_attn<<<NOUT, 256, 0, stream>>>(x, ws_, wd_, we_, easum, counts, slist, aed, z);
  k_gemm1<<<dim3(72,4), 256, 0, stream>>>(z, W, bias, h2);
  k_gemm2<<<144, 256, 0, stream>>>(h2, fcW, fcb, out);
}